// Round 1
// baseline (1087.332 us; speedup 1.0000x reference)
//
#include <hip/hip_runtime.h>
#include <math.h>

#define B   32
#define H   16
#define DK  64
#define DM  1024
#define TC  4096
#define NS  8            // T splits in flash-decode
#define DSL 8            // d-slices in projection split-K
#define LOG2E 1.44269504088896340736f
#define SCALE 0.125f     // 1/sqrt(DK)

// ---------------------------------------------------------------------------
// Projection partial: part[(m*DSL+ds)][j][b] = sum_{d in slice} in[b][d]*w[j][d]
// Block: (jt, ds, m), 256 threads. in tile (32 b x 128 d) staged in LDS,
// b mapped to lanes -> weight loads are half-wave broadcasts, reduction is
// serial in-thread over d (no shuffles, no atomics).
// ---------------------------------------------------------------------------
__global__ __launch_bounds__(256) void proj_partial(
    const float* __restrict__ in,     // [32][1024]
    const float* __restrict__ w0,
    const float* __restrict__ w1,
    const float* __restrict__ w2,
    float* __restrict__ part)         // [(m*DSL+ds)][1024][32]
{
    const int jt = blockIdx.x;        // 0..15 (64 j per block)
    const int ds = blockIdx.y;        // 0..7  (128 d per slice)
    const int m  = blockIdx.z;
    const float* __restrict__ w = (m == 0) ? w0 : (m == 1) ? w1 : w2;

    __shared__ float qs[32 * 132];    // 32 rows x 128 d, padded to 132
    const float4* in4 = (const float4*)in;
    float4* qs4 = (float4*)qs;
    const int tid = threadIdx.x;

    #pragma unroll
    for (int k = 0; k < 4; k++) {
        int g   = tid + k * 256;      // 0..1023 float4s
        int b   = g >> 5;
        int dd4 = g & 31;
        qs4[b * 33 + dd4] = in4[b * 256 + ds * 32 + dd4];
    }
    __syncthreads();

    const int wave  = tid >> 6;
    const int lane  = tid & 63;
    const int jhalf = lane >> 5;      // which j of the pair
    const int b     = lane & 31;      // batch across lanes
    const float4* w4 = (const float4*)w;

    #pragma unroll
    for (int p = 0; p < 8; p++) {
        int j = jt * 64 + wave * 16 + p * 2 + jhalf;
        float acc = 0.f;
        #pragma unroll
        for (int it = 0; it < 32; it++) {
            float4 wv = w4[j * 256 + ds * 32 + it];   // broadcast per half-wave
            float4 qv = qs4[b * 33 + it];             // conflict-free (33 stride)
            acc += wv.x * qv.x + wv.y * qv.y + wv.z * qv.z + wv.w * qv.w;
        }
        part[((m * DSL + ds) * DM + j) * 32 + b] = acc;  // coalesced (b fastest)
    }
}

// ---------------------------------------------------------------------------
// Sum the DSL partials + bias. out[m][b][1024].
// ---------------------------------------------------------------------------
__global__ __launch_bounds__(256) void reduce_part(
    const float* __restrict__ part,
    const float* __restrict__ b0,
    const float* __restrict__ b1,
    const float* __restrict__ b2,
    float* __restrict__ out)
{
    const int gid = blockIdx.x * 256 + threadIdx.x;
    const int m = gid >> 15;          // /32768
    const int r = gid & 32767;        // j*32 + b
    const int j = r >> 5;
    const int b = r & 31;
    float s = 0.f;
    #pragma unroll
    for (int ds = 0; ds < DSL; ds++)
        s += part[(m * DSL + ds) * (DM * 32) + r];
    const float* __restrict__ bias = (m == 0) ? b0 : (m == 1) ? b1 : b2;
    out[m * (B * DM) + b * DM + j] = s + bias[j];
}

// ---------------------------------------------------------------------------
// Flash-decode partition: block (split,h,b) streams 512 K rows + 512 V rows,
// local softmax (exp2 domain), writes unnormalized partial O + (m,l).
// ---------------------------------------------------------------------------
__global__ __launch_bounds__(256) void attn_part_kernel(
    const float* __restrict__ qh,     // [B][H*DK]
    const float* __restrict__ Kc,     // [B][H][TC][DK]
    const float* __restrict__ Vc,
    float* __restrict__ part_O,       // [bh][NS][64]
    float* __restrict__ part_ml)      // [bh][NS][2]
{
    const int split = blockIdx.x;
    const int h = blockIdx.y;
    const int b = blockIdx.z;
    const int bh = b * H + h;
    const int t0 = split * (TC / NS);   // 512-row chunk

    __shared__ float sp[512];
    __shared__ float so[16 * 64];
    __shared__ float red[8];

    const int tid = threadIdx.x;
    const int r = tid >> 4;             // 16 rows in flight
    const int c = tid & 15;             // 16 float4s per row (64 d)

    const float4* q4p = (const float4*)(qh + b * DM + h * DK);
    const float4 q4 = q4p[c];

    const float4* K4 = (const float4*)(Kc + (size_t)bh * TC * DK);
    const float4* V4 = (const float4*)(Vc + (size_t)bh * TC * DK);
    const float sc = SCALE * LOG2E;

    // ---- scores for 512 rows ----
    #pragma unroll 4
    for (int it = 0; it < 32; it++) {
        int t = t0 + it * 16 + r;
        float4 k4 = K4[t * 16 + c];
        float d = q4.x * k4.x + q4.y * k4.y + q4.z * k4.z + q4.w * k4.w;
        d += __shfl_xor(d, 1);
        d += __shfl_xor(d, 2);
        d += __shfl_xor(d, 4);
        d += __shfl_xor(d, 8);
        if (c == 0) sp[it * 16 + r] = d * sc;
    }
    __syncthreads();

    // ---- block max ----
    float v0 = sp[tid], v1 = sp[tid + 256];
    float mx = fmaxf(v0, v1);
    #pragma unroll
    for (int o = 32; o; o >>= 1) mx = fmaxf(mx, __shfl_xor(mx, o));
    if ((tid & 63) == 0) red[tid >> 6] = mx;
    __syncthreads();
    mx = fmaxf(fmaxf(red[0], red[1]), fmaxf(red[2], red[3]));

    // ---- exp + sum (overwrite scores with p) ----
    float p0 = exp2f(v0 - mx);
    float p1 = exp2f(v1 - mx);
    sp[tid] = p0;
    sp[tid + 256] = p1;
    float sm = p0 + p1;
    #pragma unroll
    for (int o = 32; o; o >>= 1) sm += __shfl_xor(sm, o);
    if ((tid & 63) == 0) red[4 + (tid >> 6)] = sm;
    __syncthreads();
    const float l = red[4] + red[5] + red[6] + red[7];

    // ---- O = sum_t p_t * V[t,:] ----
    float4 acc = make_float4(0.f, 0.f, 0.f, 0.f);
    #pragma unroll 4
    for (int it = 0; it < 32; it++) {
        int t = t0 + it * 16 + r;
        float4 vv = V4[t * 16 + c];
        float pp = sp[it * 16 + r];
        acc.x += pp * vv.x;
        acc.y += pp * vv.y;
        acc.z += pp * vv.z;
        acc.w += pp * vv.w;
    }
    float4* so4 = (float4*)so;
    so4[r * 16 + c] = acc;
    __syncthreads();

    if (tid < 64) {
        float od = 0.f;
        #pragma unroll
        for (int rr = 0; rr < 16; rr++) od += so[rr * 64 + tid];
        part_O[(bh * NS + split) * 64 + tid] = od;
    }
    if (tid == 0) {
        part_ml[(bh * NS + split) * 2 + 0] = mx;
        part_ml[(bh * NS + split) * 2 + 1] = l;
    }
}

// ---------------------------------------------------------------------------
// Merge NS partials + the freshly-projected token (m=s_new, l=1, O=v_new).
// One wave per (b,h). x[b][h*64+d] = O/L.
// ---------------------------------------------------------------------------
__global__ __launch_bounds__(64) void combine_kernel(
    const float* __restrict__ qh,
    const float* __restrict__ kn,
    const float* __restrict__ vn,
    const float* __restrict__ part_O,
    const float* __restrict__ part_ml,
    float* __restrict__ x)
{
    const int bh = blockIdx.x;
    const int b = bh >> 4;
    const int h = bh & 15;
    const int d = threadIdx.x;
    const int off = b * DM + h * DK + d;

    const float qv = qh[off];
    const float kv = kn[off];
    const float vv = vn[off];

    float s = qv * kv;
    s += __shfl_xor(s, 1);
    s += __shfl_xor(s, 2);
    s += __shfl_xor(s, 4);
    s += __shfl_xor(s, 8);
    s += __shfl_xor(s, 16);
    s += __shfl_xor(s, 32);
    const float snew = s * (SCALE * LOG2E);

    float mvals[NS], lvals[NS];
    float M = snew;
    #pragma unroll
    for (int i = 0; i < NS; i++) {
        mvals[i] = part_ml[(bh * NS + i) * 2 + 0];
        lvals[i] = part_ml[(bh * NS + i) * 2 + 1];
        M = fmaxf(M, mvals[i]);
    }
    const float wn = exp2f(snew - M);
    float L = wn;
    float od = vv * wn;
    #pragma unroll
    for (int i = 0; i < NS; i++) {
        float wgt = exp2f(mvals[i] - M);
        L += lvals[i] * wgt;
        od += part_O[(bh * NS + i) * 64 + d] * wgt;
    }
    x[bh * 64 + d] = od / L;   // bh*64 == b*1024 + h*64
}

// ---------------------------------------------------------------------------
extern "C" void kernel_launch(void* const* d_in, const int* in_sizes, int n_in,
                              void* d_out, int out_size, void* d_ws, size_t ws_size,
                              hipStream_t stream) {
    const float* q  = (const float*)d_in[0];
    const float* Kc = (const float*)d_in[1];
    const float* Vc = (const float*)d_in[2];
    const float* wq = (const float*)d_in[3];
    const float* bq = (const float*)d_in[4];
    const float* wk = (const float*)d_in[5];
    const float* bk = (const float*)d_in[6];
    const float* wv = (const float*)d_in[7];
    const float* bv = (const float*)d_in[8];
    const float* wo = (const float*)d_in[9];
    const float* bo = (const float*)d_in[10];
    float* out = (float*)d_out;
    float* ws = (float*)d_ws;

    // workspace layout (floats)
    float* part   = ws;                       // 3*8*32768  = 786432
    float* qkv    = ws + 786432;              // 3*32768    =  98304 (qh,kn,vn)
    float* partO  = ws + 786432 + 98304;      // 512*8*64   = 262144
    float* partml = ws + 786432 + 98304 + 262144;          //  8192
    float* x      = ws + 786432 + 98304 + 262144 + 8192;   // 32768
    float* qh = qkv;
    float* kn = qkv + 32768;
    float* vn = qkv + 65536;

    // 1) QKV projections (split-K partials, then reduce+bias)
    proj_partial<<<dim3(16, DSL, 3), 256, 0, stream>>>(q, wq, wk, wv, part);
    reduce_part<<<dim3(3 * 32768 / 256), 256, 0, stream>>>(part, bq, bk, bv, qkv);

    // 2) flash-decode over the 4096 cached positions
    attn_part_kernel<<<dim3(NS, H, B), 256, 0, stream>>>(qh, Kc, Vc, partO, partml);

    // 3) merge partials + new token
    combine_kernel<<<dim3(B * H), 64, 0, stream>>>(qh, kn, vn, partO, partml, x);

    // 4) output projection
    proj_partial<<<dim3(16, DSL, 1), 256, 0, stream>>>(x, wo, wo, wo, part);
    reduce_part<<<dim3(32768 / 256), 256, 0, stream>>>(part, bo, bo, bo, out);
}